// Round 10
// baseline (723.514 us; speedup 1.0000x reference)
//
#include <hip/hip_runtime.h>
#include <stdint.h>

#define NN    6000
#define KNNC  10
#define MM    (NN * 2 * (KNNC + 1))   // 132000
#define DD    (2 * NN)                // 12000
#define LCH   3                       // hidden layers (LC-1)
#define BLK   256

#define FB    1032                    // fused blocks: 128 MLP rows each
#define NV    ((long long)DD * DD / 4)   // 36,000,000 float4s
#define SCGRID ((MM + BLK - 1) / BLK)    // 516

// Round-10: recombination of the measured-best pieces from the 9-round
// ledger. Cross-round decomposition (R2 anchored: fused=379 direct,
// poison=375 direct -> plain-atomicAdd scatter = 126us CAS; R6/R8: unsafe
// scatter ~=30us) shows R1's wave-specialized fused fill+MLP did BOTH jobs
// in ~190us, while the best sequential split (R9) needs 94+180=274us for
// the same work -- MLP time is occupancy-invariant (~180us at 3..20
// waves/CU, any weight path), so the fill's HBM drain hides inside it for
// free. R4's "fused is bad" conclusion was a two-changes-at-once error:
// the sequential split cost +60 while the atomics swap saved -100.
// Structure: R1's exact MLP body (global per-k float4 weight loads,
// unroll-8 k-loop, h in per-wave LDS [k][lane], no barriers) + 2 fill
// + 2 MLP waves per block (rotating roles across blocks), grid 1032.
// At 144 VGPR -> 3 blocks/CU: 6 MLP + 6 fill waves/CU (R1 had 3+9; fill
// needs only ~3.3 waves/CU for 6.15 TB/s). Scatter: separate kernel,
// unsafeAtomicAdd (native global_atomic_add_f32, no CAS), after the fill
// completes (atomics must not race the zeroing).
__global__ __launch_bounds__(BLK) void fused_fill_mlp(
    const float* __restrict__ CK,    // [MM,3]
    const float* __restrict__ Win,   // [3,64]
    const float* __restrict__ bin,   // [64]
    const float* __restrict__ Whid,  // [3,64,64]
    const float* __restrict__ bhid,  // [3,64]
    const float* __restrict__ Wout,  // [64,4]
    const float* __restrict__ bout,  // [4]
    float* __restrict__ vals,        // [MM,2] (workspace)
    float* __restrict__ out)         // [DD*DD], zero-filled here
{
    __shared__ float sH[2][64 * 64]; // per-MLP-wave activations [k][lane], 2x16KiB

    const int tid  = threadIdx.x;
    const int wave = tid >> 6;
    const int lane = tid & 63;
    const int role = (wave + blockIdx.x) & 3;   // rotate roles across SIMDs

    if (role >= 2) {
        // ---- fill: 2 waves per block stream float4 zeros ----
        const int fw = role - 2;                               // 0..1
        const long long ft = ((long long)blockIdx.x * 2 + fw) * 64 + lane;
        const long long stride = (long long)FB * 2 * 64;       // 132096
        float4 z = make_float4(0.f, 0.f, 0.f, 0.f);
        float4* outv = (float4*)out;
        for (long long i = ft; i < NV; i += stride) outv[i] = z;
        return;
    }

    // ---- MLP: 2 waves per block, one row per lane (R1's proven body) ----
    const int mw = role;                         // 0..1
    const int m0 = blockIdx.x * 128 + mw * 64 + lane;
    const int m  = m0 < MM ? m0 : MM - 1;        // clamp loads, guard store

    const float x0 = CK[m * 3 + 0];
    const float x1 = CK[m * 3 + 1];
    const float x2 = CK[m * 3 + 2];

    float* __restrict__ hcol = sH[mw] + lane;    // h[k] lives at hcol[k*64]

    // Input layer 3 -> 64; weight/bias reads wave-uniform (broadcast).
#pragma unroll
    for (int j = 0; j < 64; j++) {
        float a = bin[j];
        a = fmaf(x0, Win[j],       a);
        a = fmaf(x1, Win[64 + j],  a);
        a = fmaf(x2, Win[128 + j], a);
        hcol[j * 64] = fmaxf(a, 0.0f);           // static addr: ds_write_b32
    }

    // Hidden layers: g_j = sum_k W[k][j] * h_k. Same-wave DS ordering ->
    // no barriers. k-loop unroll x8 batches the uniform weight loads.
#pragma unroll 1
    for (int l = 0; l < LCH; l++) {
        const float4* __restrict__ W4 = (const float4*)(Whid + (l << 12));
        const float*  __restrict__ bh = bhid + (l << 6);
        float g[64];
#pragma unroll
        for (int j = 0; j < 64; j++) g[j] = bh[j];
#pragma unroll 8
        for (int k = 0; k < 64; k++) {
            const float hk = hcol[k * 64];       // ds_read_b32 (2-way alias: free)
            const float4* __restrict__ Wk = W4 + (k << 4);   // row k: 16 float4s
#pragma unroll
            for (int j4 = 0; j4 < 16; j4++) {
                float4 w = Wk[j4];               // wave-uniform batch
                g[j4 * 4 + 0] = fmaf(w.x, hk, g[j4 * 4 + 0]);
                g[j4 * 4 + 1] = fmaf(w.y, hk, g[j4 * 4 + 1]);
                g[j4 * 4 + 2] = fmaf(w.z, hk, g[j4 * 4 + 2]);
                g[j4 * 4 + 3] = fmaf(w.w, hk, g[j4 * 4 + 3]);
            }
        }
#pragma unroll
        for (int j = 0; j < 64; j++) hcol[j * 64] = fmaxf(g[j], 0.0f);
    }

    // Output layer collapsed over mi: vals[:,mj] = C[:,mj] + C[:,mj+2]
    float v0 = bout[0] + bout[2];
    float v1 = bout[1] + bout[3];
#pragma unroll 8
    for (int k = 0; k < 64; k++) {
        float4 wo = *((const float4*)Wout + k);
        const float hk = hcol[k * 64];
        v0 = fmaf(hk, wo.x + wo.z, v0);
        v1 = fmaf(hk, wo.y + wo.w, v1);
    }
    if (m0 < MM) *(float2*)(vals + 2 * m0) = make_float2(v0, v1);
}

__global__ __launch_bounds__(BLK) void scatter_add(
    const float* __restrict__ vals,   // [MM,2]
    const int* __restrict__ coo,      // [2,MM]
    float* __restrict__ out)          // [DD*DD]
{
    const int t = blockIdx.x * BLK + threadIdx.x;
    if (t >= MM) return;
    const int r2 = coo[t] * 2;        // row index * MODES
    const int c2 = coo[MM + t] * 2;   // col index * MODES
    const float2 v = *(const float2*)(vals + 2 * t);
    // mj=0: element (r2, c2); mj=1: element (r2+1, c2+1) = +DD+1 flat
    const long long f0 = (long long)r2 * DD + c2;
    // Native global_atomic_add_f32 (fire-and-forget), not a CAS retry loop.
    unsafeAtomicAdd(out + f0, v.x);
    unsafeAtomicAdd(out + f0 + DD + 1, v.y);
}

extern "C" void kernel_launch(void* const* d_in, const int* in_sizes, int n_in,
                              void* d_out, int out_size, void* d_ws, size_t ws_size,
                              hipStream_t stream) {
    const float* CK   = (const float*)d_in[0];
    const float* Win  = (const float*)d_in[1];
    const float* bin  = (const float*)d_in[2];
    const float* Whid = (const float*)d_in[3];
    const float* bhid = (const float*)d_in[4];
    const float* Wout = (const float*)d_in[5];
    const float* bout = (const float*)d_in[6];
    const int* coo    = (const int*)d_in[7];
    float* out        = (float*)d_out;
    float* vals       = (float*)d_ws;

    fused_fill_mlp<<<FB, BLK, 0, stream>>>(
        CK, Win, bin, Whid, bhid, Wout, bout, vals, out);
    scatter_add<<<SCGRID, BLK, 0, stream>>>(vals, coo, out);
}

// Round 11
// 650.243 us; speedup vs baseline: 1.1127x; 1.1127x over previous
//
#include <hip/hip_runtime.h>
#include <stdint.h>

#define NN    6000
#define KNNC  10
#define MM    (NN * 2 * (KNNC + 1))   // 132000
#define DD    (2 * NN)                // 12000
#define LCH   3                       // hidden layers (LC-1)
#define BLK   256

#define RB     128                     // rows per MLP block
#define RPL    2                       // rows per lane
#define MLPB   1032                    // MLP blocks (1032*128 = 132096 rows)
#define FILLB  2064                    // fill blocks
#define GRID   (MLPB + FILLB)          // 3096, interleaved 1:2
#define NV     ((long long)DD * DD / 4)   // 36,000,000 float4s
#define SCGRID ((MM + BLK - 1) / BLK)     // 516

// Round-11: recombine the two measured-best components that were never
// tested together. Ledger: (a) BLOCK-specialized overlap (R3) did fill+MLP
// in ~216us with a 250us-standalone MLP body -- overlap efficiency ~100%,
// because fill blocks drain/backfill independently (no R2-style intra-block
// tail); (b) R9's s_load-lockstep RB=128 MLP body is the best standalone
// (~150-160us). R10 proved intra-block wave-ratio tuning regresses (2+2 ->
// 318us: co-resident MLP waves contend on the weight path, stalls ADD).
// Structure: every 3rd block = R9 MLP body writing vals (scatter NOT fused:
// atomics would race the concurrent zero-fill), others = pure float4 zero
// stream. Scatter = separate unsafeAtomicAdd kernel (~30us, proven).
__global__ __launch_bounds__(BLK, 4) void fused_fill_mlp(
    const float* __restrict__ CK,    // [MM,3]
    const float* __restrict__ Win,   // [3,64]
    const float* __restrict__ bin,   // [64]
    const float* __restrict__ Whid,  // [3,64,64]
    const float* __restrict__ bhid,  // [3,64]
    const float* __restrict__ Wout,  // [64,4]
    const float* __restrict__ bout,  // [4]
    float* __restrict__ vals,        // [MM,2] (workspace)
    float* __restrict__ out)         // [DD*DD], zero-filled here
{
    __shared__ float sH[64 * RB];    // activations [k][row], row=lane*2+r, 32 KiB

    const int bid = blockIdx.x;
    const int tid = threadIdx.x;

    if (bid % 3 != 2) {
        // ---- fill block: stream float4 zeros (6.15 TB/s path) ----
        const int fid = (bid / 3) * 2 + (bid % 3);            // 0..2063
        long long i = (long long)fid * BLK + tid;
        const long long stride = (long long)FILLB * BLK;      // 528384
        float4 z = make_float4(0.f, 0.f, 0.f, 0.f);
        float4* outv = (float4*)out;
        for (; i < NV; i += stride) outv[i] = z;
        return;
    }

    // ---- MLP block: R9's s_load-lockstep body, 128 rows ----
    const int wave = tid >> 6;
    const int lane = tid & 63;
    // Wave-uniform channel offset in an SGPR -> weight loads scalarize.
    const int jo = __builtin_amdgcn_readfirstlane((tid >> 6) << 4);

    const int rbase = (bid / 3) * RB;
    const int mb0   = rbase + lane * 2;        // lane's first row (even)
    const int mb    = mb0 < MM ? mb0 : MM - 2; // clamp loads, guard stores

    // Lane's 2 rows of inputs: 6 consecutive floats -> 3 float2.
    const float2 ca = *(const float2*)(CK + mb * 3);      // x0r0 x1r0
    const float2 cb = *(const float2*)(CK + mb * 3 + 2);  // x2r0 x0r1
    const float2 cc = *(const float2*)(CK + mb * 3 + 4);  // x1r1 x2r1
    const float x0[RPL] = {ca.x, cb.y};
    const float x1[RPL] = {ca.y, cc.x};
    const float x2[RPL] = {cb.x, cc.y};

    // Input layer: this wave's 16 channels for its 2 packed rows.
#pragma unroll
    for (int jj = 0; jj < 16; jj++) {
        const int j = jo + jj;
        const float w0 = Win[j], w1 = Win[64 + j], w2 = Win[128 + j];  // s_load
        const float bj = bin[j];
        float2 hv;
        hv.x = fmaxf(fmaf(x2[0], w2, fmaf(x1[0], w1, fmaf(x0[0], w0, bj))), 0.f);
        hv.y = fmaxf(fmaf(x2[1], w2, fmaf(x1[1], w1, fmaf(x0[1], w0, bj))), 0.f);
        *(float2*)(sH + j * RB + lane * 2) = hv;
    }
    __syncthreads();

    // Hidden layers, barrier-lockstep (all waves on the same 16KB W -> K$-hot).
#pragma unroll 1
    for (int l = 0; l < LCH; l++) {
        const float* __restrict__ Wl = Whid + (l << 12) + jo;  // uniform SGPR base
        const float* __restrict__ bh = bhid + (l << 6) + jo;

        float g[RPL][16];
#pragma unroll
        for (int jj = 0; jj < 16; jj++) {
            const float bj = bh[jj];           // s_load
            g[0][jj] = bj;
            g[1][jj] = bj;
        }

#pragma unroll 4
        for (int k = 0; k < 64; k++) {
            // This wave's 16-channel weight slice: 64B uniform -> s_load.
            const float4 wa = *(const float4*)(Wl + (k << 6));
            const float4 wb = *(const float4*)(Wl + (k << 6) + 4);
            const float4 wc = *(const float4*)(Wl + (k << 6) + 8);
            const float4 wd = *(const float4*)(Wl + (k << 6) + 12);
            // Lane's 2 packed rows of h_k: one b64.
            const float2 hv = *(const float2*)(sH + k * RB + lane * 2);
            const float hk[RPL] = {hv.x, hv.y};
#pragma unroll
            for (int r = 0; r < RPL; r++) {
                g[r][0]  = fmaf(wa.x, hk[r], g[r][0]);
                g[r][1]  = fmaf(wa.y, hk[r], g[r][1]);
                g[r][2]  = fmaf(wa.z, hk[r], g[r][2]);
                g[r][3]  = fmaf(wa.w, hk[r], g[r][3]);
                g[r][4]  = fmaf(wb.x, hk[r], g[r][4]);
                g[r][5]  = fmaf(wb.y, hk[r], g[r][5]);
                g[r][6]  = fmaf(wb.z, hk[r], g[r][6]);
                g[r][7]  = fmaf(wb.w, hk[r], g[r][7]);
                g[r][8]  = fmaf(wc.x, hk[r], g[r][8]);
                g[r][9]  = fmaf(wc.y, hk[r], g[r][9]);
                g[r][10] = fmaf(wc.z, hk[r], g[r][10]);
                g[r][11] = fmaf(wc.w, hk[r], g[r][11]);
                g[r][12] = fmaf(wd.x, hk[r], g[r][12]);
                g[r][13] = fmaf(wd.y, hk[r], g[r][13]);
                g[r][14] = fmaf(wd.z, hk[r], g[r][14]);
                g[r][15] = fmaf(wd.w, hk[r], g[r][15]);
            }
        }
        __syncthreads();   // all reads of sH for layer l complete

        // relu + writeback: 16 b64 (2 packed rows per channel).
#pragma unroll
        for (int jj = 0; jj < 16; jj++) {
            float2 hv;
            hv.x = fmaxf(g[0][jj], 0.f);
            hv.y = fmaxf(g[1][jj], 0.f);
            *(float2*)(sH + (jo + jj) * RB + lane * 2) = hv;
        }
        __syncthreads();   // h ready for next layer / output
    }

    // Output layer collapsed over mi: v[:,mj] = C[:,mj] + C[:,mj+2].
    // All 4 waves compute identical v for the same rows; wave 0 writes.
    float v0[RPL], v1[RPL];
    const float b02 = bout[0] + bout[2], b13 = bout[1] + bout[3];
#pragma unroll
    for (int r = 0; r < RPL; r++) { v0[r] = b02; v1[r] = b13; }
#pragma unroll 8
    for (int k = 0; k < 64; k++) {
        const float4 wo = ((const float4*)Wout)[k];     // s_load
        const float wxz = wo.x + wo.z, wyw = wo.y + wo.w;
        const float2 hv = *(const float2*)(sH + k * RB + lane * 2);
        v0[0] = fmaf(hv.x, wxz, v0[0]);  v1[0] = fmaf(hv.x, wyw, v1[0]);
        v0[1] = fmaf(hv.y, wxz, v0[1]);  v1[1] = fmaf(hv.y, wyw, v1[1]);
    }
    if (wave == 0 && mb0 < MM) {
        // rows mb0, mb0+1: vals[2*mb0 .. 2*mb0+3], 16B-aligned -> one float4.
        *(float4*)(vals + 2 * mb0) = make_float4(v0[0], v1[0], v0[1], v1[1]);
    }
}

__global__ __launch_bounds__(BLK) void scatter_add(
    const float* __restrict__ vals,   // [MM,2]
    const int* __restrict__ coo,      // [2,MM]
    float* __restrict__ out)          // [DD*DD]
{
    const int t = blockIdx.x * BLK + threadIdx.x;
    if (t >= MM) return;
    const int r2 = coo[t] * 2;        // row index * MODES
    const int c2 = coo[MM + t] * 2;   // col index * MODES
    const float2 v = *(const float2*)(vals + 2 * t);
    // mj=0: element (r2, c2); mj=1: element (r2+1, c2+1) = +DD+1 flat
    const long long f0 = (long long)r2 * DD + c2;
    // Native global_atomic_add_f32 (fire-and-forget), not a CAS retry loop.
    unsafeAtomicAdd(out + f0, v.x);
    unsafeAtomicAdd(out + f0 + DD + 1, v.y);
}

extern "C" void kernel_launch(void* const* d_in, const int* in_sizes, int n_in,
                              void* d_out, int out_size, void* d_ws, size_t ws_size,
                              hipStream_t stream) {
    const float* CK   = (const float*)d_in[0];
    const float* Win  = (const float*)d_in[1];
    const float* bin  = (const float*)d_in[2];
    const float* Whid = (const float*)d_in[3];
    const float* bhid = (const float*)d_in[4];
    const float* Wout = (const float*)d_in[5];
    const float* bout = (const float*)d_in[6];
    const int* coo    = (const int*)d_in[7];
    float* out        = (float*)d_out;
    float* vals       = (float*)d_ws;

    fused_fill_mlp<<<GRID, BLK, 0, stream>>>(
        CK, Win, bin, Whid, bhid, Wout, bout, vals, out);
    scatter_add<<<SCGRID, BLK, 0, stream>>>(vals, coo, out);
}